// Round 2
// baseline (220.837 us; speedup 1.0000x reference)
//
#include <hip/hip_runtime.h>

// IPUNeighborListMD — dense masked displacement matrix.
// out[m,i,j,c] = (pos[m,j,c] - pos[m,i,c]) * (|r_j - r_i|^2 < 49 && i != j)
// out: [64, 512, 512, 3] float32 (~201 MB)  -> write-BW bound.
// input: positions [64,512,3]; dtype (bf16 vs f32) sniffed on-device:
//   f32 in [0,20): bits 8..15 are random mantissa bits (often > 0x41)
//   bf16 pair:     bits 8..15 are the high byte of a bf16 in [0,20) (<= 0x41)

#define NMOL   64
#define NATOM  512
#define RC2    49.0f      // (5.0 + 2.0)^2, exact in f32
#define SLICES 32         // blocks per molecule; each block does 16 rows

typedef unsigned int   u32;
typedef unsigned short u16;

__device__ __forceinline__ float bf2f(u16 u) {
    union { u32 u; float f; } v; v.u = ((u32)u) << 16; return v.f;
}

__global__ __launch_bounds__(256)
void nbl_kernel(const void* __restrict__ pos_raw, float* __restrict__ out) {
    __shared__ int s_f32;
    const int t = threadIdx.x;

    // ---- input dtype sniff (wave-uniform result, negligible cost) ----
    if (t == 0) s_f32 = 0;
    __syncthreads();
    {
        const u32* w = (const u32*)pos_raw;
        const u32 a = w[t];
        const u32 b = w[t + 256];
        if ((((a >> 8) & 0xffu) > 0x41u) || (((b >> 8) & 0xffu) > 0x41u))
            s_f32 = 1;   // benign same-value race
    }
    __syncthreads();
    const bool is_f32 = (s_f32 != 0);

    const int bx     = blockIdx.x;
    const int m      = bx >> 5;              // molecule
    const int slice  = bx & (SLICES - 1);
    const int lane   = t & 63;
    const int wave   = t >> 6;
    const int i_base = slice * 16 + wave * 4;  // 4 waves x 4 rows = 16 rows/block

    const float* pm32 = (const float*)pos_raw + (size_t)m * (NATOM * 3);
    const u16*   pm16 = (const u16*)pos_raw   + (size_t)m * (NATOM * 3);

    // Each lane owns 8 consecutive atoms j: 24 floats, cached in registers.
    float pj[24];
    if (is_f32) {
        const float4* p4 = (const float4*)pm32 + lane * 6;   // 96 B / lane
        #pragma unroll
        for (int k = 0; k < 6; ++k) {
            const float4 q = p4[k];
            pj[4*k+0] = q.x; pj[4*k+1] = q.y; pj[4*k+2] = q.z; pj[4*k+3] = q.w;
        }
    } else {
        const uint4* p4 = (const uint4*)pm16 + lane * 3;     // 48 B / lane
        u32 words[12];
        #pragma unroll
        for (int k = 0; k < 3; ++k) {
            const uint4 q = p4[k];
            words[4*k+0] = q.x; words[4*k+1] = q.y;
            words[4*k+2] = q.z; words[4*k+3] = q.w;
        }
        #pragma unroll
        for (int k = 0; k < 12; ++k) {
            pj[2*k]   = bf2f((u16)(words[k] & 0xffffu));
            pj[2*k+1] = bf2f((u16)(words[k] >> 16));
        }
    }

    const int j0 = lane * 8;

    #pragma unroll
    for (int r = 0; r < 4; ++r) {
        const int i = i_base + r;
        float rix, riy, riz;   // wave-uniform broadcast reads (L1/L2 hit)
        if (is_f32) {
            rix = pm32[3*i+0]; riy = pm32[3*i+1]; riz = pm32[3*i+2];
        } else {
            rix = bf2f(pm16[3*i+0]); riy = bf2f(pm16[3*i+1]); riz = bf2f(pm16[3*i+2]);
        }

        float o[24];
        #pragma unroll
        for (int jj = 0; jj < 8; ++jj) {
            // Exact numpy f32 semantics: rounded sub/mul, sequential rounded
            // adds ((x+y)+z), NO fma contraction (cutoff-boundary mask!).
            const float dx = __fsub_rn(pj[3*jj+0], rix);
            const float dy = __fsub_rn(pj[3*jj+1], riy);
            const float dz = __fsub_rn(pj[3*jj+2], riz);
            const float d2 = __fadd_rn(__fadd_rn(__fmul_rn(dx, dx),
                                                 __fmul_rn(dy, dy)),
                                       __fmul_rn(dz, dz));
            const bool keep = (d2 < RC2) && ((j0 + jj) != i);
            o[3*jj+0] = keep ? dx : 0.0f;
            o[3*jj+1] = keep ? dy : 0.0f;
            o[3*jj+2] = keep ? dz : 0.0f;
        }

        // out row = (m*512 + i): 1536 f32 = 384 float4; lane writes 6 float4.
        const size_t row = (size_t)(m * NATOM + i);
        float4* op = (float4*)out + row * 384 + lane * 6;
        #pragma unroll
        for (int k = 0; k < 6; ++k)
            op[k] = make_float4(o[4*k+0], o[4*k+1], o[4*k+2], o[4*k+3]);
    }
}

extern "C" void kernel_launch(void* const* d_in, const int* in_sizes, int n_in,
                              void* d_out, int out_size, void* d_ws, size_t ws_size,
                              hipStream_t stream) {
    const void* pos = d_in[0];
    float* out = (float*)d_out;
    dim3 grid(NMOL * SLICES);   // 2048 blocks
    dim3 block(256);
    nbl_kernel<<<grid, block, 0, stream>>>(pos, out);
}

// Round 3
// 194.351 us; speedup vs baseline: 1.1363x; 1.1363x over previous
//
#include <hip/hip_runtime.h>

// IPUNeighborListMD — dense masked displacement matrix.
// out[m,i,j,c] = (pos[m,j,c] - pos[m,i,c]) * (|r_j - r_i|^2 < 49 && i != j)
// out: [64, 512, 512, 3] float32 (~201 MB)  -> write-BW bound.
//
// R2: 220 us at ~0.9 TB/s — stores had 96 B lane stride (6 float4/lane),
// defeating write coalescing. R3: wave-local LDS transpose so global stores
// have 16 B lane stride (fillBuffer pattern, ~6.6 TB/s measured ceiling).

#define NMOL   64
#define NATOM  512
#define RC2    49.0f      // (5.0 + 2.0)^2, exact in f32
#define SLICES 32         // blocks per molecule; each block does 16 rows

typedef unsigned int   u32;
typedef unsigned short u16;

__device__ __forceinline__ float bf2f(u16 u) {
    union { u32 u; float f; } v; v.u = ((u32)u) << 16; return v.f;
}

__global__ __launch_bounds__(256)
void nbl_kernel(const void* __restrict__ pos_raw, float* __restrict__ out) {
    __shared__ float s_row[4][NATOM * 3];   // 6 KB per wave, wave-private
    __shared__ int s_f32;
    const int t = threadIdx.x;

    // ---- input dtype sniff (f32 vs packed bf16), wave-uniform result ----
    if (t == 0) s_f32 = 0;
    __syncthreads();
    {
        const u32* w = (const u32*)pos_raw;
        const u32 a = w[t];
        const u32 b = w[t + 256];
        if ((((a >> 8) & 0xffu) > 0x41u) || (((b >> 8) & 0xffu) > 0x41u))
            s_f32 = 1;   // benign same-value race
    }
    __syncthreads();
    const bool is_f32 = (s_f32 != 0);

    const int bx     = blockIdx.x;
    const int m      = bx >> 5;                // molecule
    const int slice  = bx & (SLICES - 1);
    const int lane   = t & 63;
    const int wave   = t >> 6;
    const int i_base = slice * 16 + wave * 4;  // 4 waves x 4 rows = 16 rows

    const float* pm32 = (const float*)pos_raw + (size_t)m * (NATOM * 3);
    const u16*   pm16 = (const u16*)pos_raw   + (size_t)m * (NATOM * 3);

    // Each lane owns 8 consecutive atoms j: 24 floats, cached in registers.
    float pj[24];
    if (is_f32) {
        const float4* p4 = (const float4*)pm32 + lane * 6;   // 96 B / lane
        #pragma unroll
        for (int k = 0; k < 6; ++k) {
            const float4 q = p4[k];
            pj[4*k+0] = q.x; pj[4*k+1] = q.y; pj[4*k+2] = q.z; pj[4*k+3] = q.w;
        }
    } else {
        const uint4* p4 = (const uint4*)pm16 + lane * 3;     // 48 B / lane
        u32 words[12];
        #pragma unroll
        for (int k = 0; k < 3; ++k) {
            const uint4 q = p4[k];
            words[4*k+0] = q.x; words[4*k+1] = q.y;
            words[4*k+2] = q.z; words[4*k+3] = q.w;
        }
        #pragma unroll
        for (int k = 0; k < 12; ++k) {
            pj[2*k]   = bf2f((u16)(words[k] & 0xffffu));
            pj[2*k+1] = bf2f((u16)(words[k] >> 16));
        }
    }

    const int j0 = lane * 8;
    float* sw = s_row[wave];

    #pragma unroll
    for (int r = 0; r < 4; ++r) {
        const int i = i_base + r;
        float rix, riy, riz;   // wave-uniform broadcast reads (L1/L2 hit)
        if (is_f32) {
            rix = pm32[3*i+0]; riy = pm32[3*i+1]; riz = pm32[3*i+2];
        } else {
            rix = bf2f(pm16[3*i+0]); riy = bf2f(pm16[3*i+1]); riz = bf2f(pm16[3*i+2]);
        }

        float o[24];
        #pragma unroll
        for (int jj = 0; jj < 8; ++jj) {
            // Exact numpy f32 semantics: rounded sub/mul, sequential rounded
            // adds ((x+y)+z), NO fma contraction (cutoff-boundary mask!).
            const float dx = __fsub_rn(pj[3*jj+0], rix);
            const float dy = __fsub_rn(pj[3*jj+1], riy);
            const float dz = __fsub_rn(pj[3*jj+2], riz);
            const float d2 = __fadd_rn(__fadd_rn(__fmul_rn(dx, dx),
                                                 __fmul_rn(dy, dy)),
                                       __fmul_rn(dz, dz));
            const bool keep = (d2 < RC2) && ((j0 + jj) != i);
            o[3*jj+0] = keep ? dx : 0.0f;
            o[3*jj+1] = keep ? dy : 0.0f;
            o[3*jj+2] = keep ? dz : 0.0f;
        }

        // ---- wave-local transpose through LDS (no __syncthreads needed;
        // compiler orders ds_write -> ds_read -> next-iter ds_write) ----
        float4* wp = (float4*)(sw + lane * 24);      // 96 B aligned
        #pragma unroll
        for (int k = 0; k < 6; ++k)
            wp[k] = make_float4(o[4*k+0], o[4*k+1], o[4*k+2], o[4*k+3]);

        // Coalesced global stores: lane stride 16 B, row = 384 float4.
        const size_t row = (size_t)(m * NATOM + i);
        float4* ob = (float4*)out + row * 384;
        const float4* sr = (const float4*)sw;
        #pragma unroll
        for (int k = 0; k < 6; ++k)
            ob[k * 64 + lane] = sr[k * 64 + lane];
    }
}

extern "C" void kernel_launch(void* const* d_in, const int* in_sizes, int n_in,
                              void* d_out, int out_size, void* d_ws, size_t ws_size,
                              hipStream_t stream) {
    const void* pos = d_in[0];
    float* out = (float*)d_out;
    dim3 grid(NMOL * SLICES);   // 2048 blocks
    dim3 block(256);
    nbl_kernel<<<grid, block, 0, stream>>>(pos, out);
}